// Round 7
// baseline (1379.945 us; speedup 1.0000x reference)
//
#include <hip/hip_runtime.h>
#include <hip/hip_bf16.h>
#include <stdint.h>

typedef int i32x4 __attribute__((ext_vector_type(4)));

// ---------------------------------------------------------------------------
// Pass 1: binarize f32 -> i8 sign (+1 / -1 / 0), 8 elems per thread-iter
// (measured at HBM roofline; unchanged)
// ---------------------------------------------------------------------------
__device__ __forceinline__ signed char sign_i8(float x) {
  return x > 0.0f ? (signed char)1 : (x < 0.0f ? (signed char)-1 : (signed char)0);
}

__global__ void binarize_i8(const float* __restrict__ in,
                            signed char* __restrict__ out,
                            int n8) {
  int idx = blockIdx.x * blockDim.x + threadIdx.x;
  int stride = gridDim.x * blockDim.x;
  const float4* in4 = (const float4*)in;
  uint2* out2 = (uint2*)out;
  for (int i = idx; i < n8; i += stride) {
    float4 a = in4[2 * i];
    float4 b = in4[2 * i + 1];
    union { signed char c[8]; uint2 u; } p;
    p.c[0] = sign_i8(a.x); p.c[1] = sign_i8(a.y);
    p.c[2] = sign_i8(a.z); p.c[3] = sign_i8(a.w);
    p.c[4] = sign_i8(b.x); p.c[5] = sign_i8(b.y);
    p.c[6] = sign_i8(b.z); p.c[7] = sign_i8(b.w);
    out2[i] = p.u;
  }
}

// ---------------------------------------------------------------------------
// Pass 2: C = A * B^T, i8 +-1 inputs, i32 acc, f32 out (exact).
// 256x256 tile, BK=64 (i8), 8 waves (2Mx4N).
// Round 7 change: 2-buffer LDS rotation (64 KiB) -> 2 blocks/CU resident
// (16 waves/CU) to cover barrier/vmcnt stalls. stage(tt+1) issued inside
// tile tt strictly after the top-of-tile barrier (race-free: all waves'
// reads of that buffer were lgkm-drained before their MFMAs, which precede
// that barrier). Same XOR swizzle / 2-phase interleave / setprio as before.
// ---------------------------------------------------------------------------
__device__ __forceinline__ void load_lds16(const void* g, void* l) {
  __builtin_amdgcn_global_load_lds(
      (const __attribute__((address_space(1))) void*)g,
      (__attribute__((address_space(3))) void*)l,
      16, 0, 0);
}

__device__ __forceinline__ void bar() {
  asm volatile("s_barrier" ::: "memory");
}
template <int N>
__device__ __forceinline__ void waitvm() {
  asm volatile("s_waitcnt vmcnt(%0)" ::"i"(N) : "memory");
}

__global__ __launch_bounds__(512, 4)
void gemm_bt_i8(const signed char* __restrict__ A,
                const signed char* __restrict__ B,
                float* __restrict__ C,
                int M, int N, int K, int nbn) {
  constexpr int BM = 256, BN = 256, BK = 64;
  // buffer = A tile (256x64 i8 = 16KB) + B tile (16KB) = 32KB; 2 buffers.
  __shared__ __attribute__((aligned(16))) char lds[2 * 32768];

  // XCD-aware bijective swizzle (grid = 32*16 = 512, multiple of 8)
  int nwg = gridDim.x;
  int bid = blockIdx.x;
  int cpx = nwg >> 3;
  int swz = (bid & 7) * cpx + (bid >> 3);
  int tm = swz / nbn;
  int tn = swz % nbn;

  const int t = threadIdx.x;
  const int lane = t & 63;
  const int wid = t >> 6;       // 0..7
  const int wm = wid >> 2;      // 0..1  (wave row: 128 rows)
  const int wn = wid & 3;       // 0..3  (wave col: 64 cols)
  const int lrow = lane & 15;
  const int kg = lane >> 4;     // 0..3 (16 contiguous k-bytes each)

  const size_t rowA0 = (size_t)tm * BM;
  const size_t rowB0 = (size_t)tn * BN;

  i32x4 acc[8][4] = {};

  const int nt = K / BK;  // 64

  // --- staging lane constants (inverse-swizzled global source) ---
  // physical byte off within a 16KB matrix region: j*8192 + wid*1024 + lane*16
  // row = off>>6 (64B rows), physical 16B block = (off>>4)&3,
  // logical block = physical ^ ((row>>1)&3)
  const int soff0 = wid * 1024 + lane * 16;
  const int srow0 = soff0 >> 6;
  const int scb0 = ((soff0 >> 4) & 3) ^ ((srow0 >> 1) & 3);
  const int soff1 = 8192 + wid * 1024 + lane * 16;
  const int srow1 = soff1 >> 6;
  const int scb1 = ((soff1 >> 4) & 3) ^ ((srow1 >> 1) & 3);

  auto stageA = [&](int tt) {
    const int b = tt & 1;
    const int k0 = tt * BK;
    load_lds16(A + (rowA0 + srow0) * K + k0 + scb0 * 16,
               lds + b * 32768 + wid * 1024);
    load_lds16(A + (rowA0 + srow1) * K + k0 + scb1 * 16,
               lds + b * 32768 + 8192 + wid * 1024);
  };
  auto stageB = [&](int tt) {
    const int b = tt & 1;
    const int k0 = tt * BK;
    load_lds16(B + (rowB0 + srow0) * K + k0 + scb0 * 16,
               lds + b * 32768 + 16384 + wid * 1024);
    load_lds16(B + (rowB0 + srow1) * K + k0 + scb1 * 16,
               lds + b * 32768 + 16384 + 8192 + wid * 1024);
  };

  // --- swizzled read column (byte) within a 64B LDS row ---
  const int rcol = ((kg ^ ((lrow >> 1) & 3)) << 4);

  // prologue: stage tile 0 only (buffer 0); tile 1 staged inside tile 0
  stageA(0); stageB(0);

  for (int tt = 0; tt < nt; ++tt) {
    const int b = tt & 1;
    // drain tile tt's loads (issued one full tile earlier, wait is short)
    waitvm<0>();
    bar();

    const char* Abase = lds + b * 32768 + (wm * 128 + lrow) * 64 + rcol;
    const char* Bbase = lds + b * 32768 + 16384 + (wn * 64 + lrow) * 64 + rcol;

    // ---- phase 0: read A frags (8) + B frags 0,1; stage A of tt+1 ----
    i32x4 af[8];
    #pragma unroll
    for (int m = 0; m < 8; ++m)
      af[m] = *(const i32x4*)(Abase + m * (16 * 64));
    i32x4 bf0 = *(const i32x4*)(Bbase);
    i32x4 bf1 = *(const i32x4*)(Bbase + 16 * 64);
    if (tt + 1 < nt) stageA(tt + 1);
    bar();
    __builtin_amdgcn_sched_barrier(0);
    __builtin_amdgcn_s_setprio(1);
    #pragma unroll
    for (int m = 0; m < 8; ++m) {
      acc[m][0] = __builtin_amdgcn_mfma_i32_16x16x64_i8(af[m], bf0, acc[m][0], 0, 0, 0);
      acc[m][1] = __builtin_amdgcn_mfma_i32_16x16x64_i8(af[m], bf1, acc[m][1], 0, 0, 0);
    }
    __builtin_amdgcn_s_setprio(0);
    bar();

    // ---- phase 1: read B frags 2,3; stage B of tt+1 ----
    i32x4 bf2 = *(const i32x4*)(Bbase + 32 * 64);
    i32x4 bf3 = *(const i32x4*)(Bbase + 48 * 64);
    if (tt + 1 < nt) stageB(tt + 1);
    bar();
    __builtin_amdgcn_sched_barrier(0);
    __builtin_amdgcn_s_setprio(1);
    #pragma unroll
    for (int m = 0; m < 8; ++m) {
      acc[m][2] = __builtin_amdgcn_mfma_i32_16x16x64_i8(af[m], bf2, acc[m][2], 0, 0, 0);
      acc[m][3] = __builtin_amdgcn_mfma_i32_16x16x64_i8(af[m], bf3, acc[m][3], 0, 0, 0);
    }
    __builtin_amdgcn_s_setprio(0);
    // tile-end barrier merged with next iteration's waitvm+bar
  }

  // --- epilogue: C/D layout col = lane&15, row = (lane>>4)*4 + r ---
  // i32 -> f32 conversion is exact (|sum| <= 4096)
  const size_t cRow0 = rowA0 + (size_t)wm * 128;
  const size_t cCol0 = rowB0 + (size_t)wn * 64;
  const int orow = kg * 4;
  #pragma unroll
  for (int m = 0; m < 8; ++m)
    #pragma unroll
    for (int n = 0; n < 4; ++n)
      #pragma unroll
      for (int r = 0; r < 4; ++r)
        C[(cRow0 + m * 16 + orow + r) * N + cCol0 + n * 16 + lrow] =
            (float)acc[m][n][r];
}

// ---------------------------------------------------------------------------
extern "C" void kernel_launch(void* const* d_in, const int* in_sizes, int n_in,
                              void* d_out, int out_size, void* d_ws, size_t ws_size,
                              hipStream_t stream) {
  const float* x = (const float*)d_in[0];
  const float* w = (const float*)d_in[1];
  float* out = (float*)d_out;

  const int K = 4096;
  const int M = in_sizes[0] / K;   // 8192
  const int N = in_sizes[1] / K;   // 4096

  signed char* xb = (signed char*)d_ws;
  signed char* wb = xb + (size_t)M * K;

  int n8x = (M * K) / 8;
  int n8w = (N * K) / 8;
  binarize_i8<<<dim3(2048), dim3(256), 0, stream>>>(x, xb, n8x);
  binarize_i8<<<dim3(2048), dim3(256), 0, stream>>>(w, wb, n8w);

  int nbm = M / 256;
  int nbn = N / 256;
  gemm_bt_i8<<<dim3(nbm * nbn), dim3(512), 0, stream>>>(
      xb, wb, out, M, N, K, nbn);
}

// Round 8
// 177.810 us; speedup vs baseline: 7.7608x; 7.7608x over previous
//
#include <hip/hip_runtime.h>
#include <hip/hip_bf16.h>
#include <stdint.h>

typedef int i32x4 __attribute__((ext_vector_type(4)));

// ---------------------------------------------------------------------------
// Pass 1: binarize f32 -> i8 sign (+1 / -1 / 0), 8 elems per thread-iter
// (measured at HBM roofline; unchanged)
// ---------------------------------------------------------------------------
__device__ __forceinline__ signed char sign_i8(float x) {
  return x > 0.0f ? (signed char)1 : (x < 0.0f ? (signed char)-1 : (signed char)0);
}

__global__ void binarize_i8(const float* __restrict__ in,
                            signed char* __restrict__ out,
                            int n8) {
  int idx = blockIdx.x * blockDim.x + threadIdx.x;
  int stride = gridDim.x * blockDim.x;
  const float4* in4 = (const float4*)in;
  uint2* out2 = (uint2*)out;
  for (int i = idx; i < n8; i += stride) {
    float4 a = in4[2 * i];
    float4 b = in4[2 * i + 1];
    union { signed char c[8]; uint2 u; } p;
    p.c[0] = sign_i8(a.x); p.c[1] = sign_i8(a.y);
    p.c[2] = sign_i8(a.z); p.c[3] = sign_i8(a.w);
    p.c[4] = sign_i8(b.x); p.c[5] = sign_i8(b.y);
    p.c[6] = sign_i8(b.z); p.c[7] = sign_i8(b.w);
    out2[i] = p.u;
  }
}

// ---------------------------------------------------------------------------
// Pass 2: C = A * B^T, i8 +-1 inputs, i32 acc, f32 out (exact).
// 256x256 tile, BK=64 (i8), 8 waves (2Mx4N), 4-buffer LDS rotation (128 KiB),
// counted vmcnt (never drained in main loop), XOR-swizzled LDS.
// Round 8: FLOW schedule -- ONE barrier per K-tile, no mid-tile barriers /
// sched_barrier / setprio. Correctness: buffer (tt+2)&3 was last read in
// tile tt-2; every wave's ds_reads of it complete (lgkm-waited by its MFMAs)
// before that wave passes the top barrier of tile tt-1, and the restage is
// issued after the top barrier of tile tt -- two barriers separate read from
// rewrite. Compiler's per-use lgkmcnt waits overlap ds_reads with MFMAs.
// __launch_bounds__(512,2): 256 reg/wave budget (acc=128 AGPR + ~96 VGPR);
// (512,4) in round 7 forced a 128-reg cap -> accumulator spill -> 3.3 GB
// scratch traffic. Do not lower the reg budget with this tile shape.
// ---------------------------------------------------------------------------
__device__ __forceinline__ void load_lds16(const void* g, void* l) {
  __builtin_amdgcn_global_load_lds(
      (const __attribute__((address_space(1))) void*)g,
      (__attribute__((address_space(3))) void*)l,
      16, 0, 0);
}

__device__ __forceinline__ void bar() {
  asm volatile("s_barrier" ::: "memory");
}
template <int N>
__device__ __forceinline__ void waitvm() {
  asm volatile("s_waitcnt vmcnt(%0)" ::"i"(N) : "memory");
}

__global__ __launch_bounds__(512, 2)
void gemm_bt_i8(const signed char* __restrict__ A,
                const signed char* __restrict__ B,
                float* __restrict__ C,
                int M, int N, int K, int nbn) {
  constexpr int BM = 256, BN = 256, BK = 64;
  // buffer = A tile (256x64 i8 = 16KB) + B tile (16KB) = 32KB; 4 buffers.
  __shared__ __attribute__((aligned(16))) char lds[4 * 32768];

  // XCD-aware bijective swizzle (grid = 32*16 = 512, multiple of 8)
  int nwg = gridDim.x;
  int bid = blockIdx.x;
  int cpx = nwg >> 3;
  int swz = (bid & 7) * cpx + (bid >> 3);
  int tm = swz / nbn;
  int tn = swz % nbn;

  const int t = threadIdx.x;
  const int lane = t & 63;
  const int wid = t >> 6;       // 0..7
  const int wm = wid >> 2;      // 0..1  (wave row: 128 rows)
  const int wn = wid & 3;       // 0..3  (wave col: 64 cols)
  const int lrow = lane & 15;
  const int kg = lane >> 4;     // 0..3 (16 contiguous k-bytes each)

  const size_t rowA0 = (size_t)tm * BM;
  const size_t rowB0 = (size_t)tn * BN;

  i32x4 acc[8][4] = {};

  const int nt = K / BK;  // 64

  // --- staging lane constants (inverse-swizzled global source) ---
  // physical byte off within a 16KB matrix region: j*8192 + wid*1024 + lane*16
  // row = off>>6 (64B rows), physical 16B block = (off>>4)&3,
  // logical block = physical ^ ((row>>1)&3)
  const int soff0 = wid * 1024 + lane * 16;
  const int srow0 = soff0 >> 6;
  const int scb0 = ((soff0 >> 4) & 3) ^ ((srow0 >> 1) & 3);
  const int soff1 = 8192 + wid * 1024 + lane * 16;
  const int srow1 = soff1 >> 6;
  const int scb1 = ((soff1 >> 4) & 3) ^ ((srow1 >> 1) & 3);

  auto stageA = [&](int tt) {
    const int b = tt & 3;
    const int k0 = tt * BK;
    load_lds16(A + (rowA0 + srow0) * K + k0 + scb0 * 16,
               lds + b * 32768 + wid * 1024);
    load_lds16(A + (rowA0 + srow1) * K + k0 + scb1 * 16,
               lds + b * 32768 + 8192 + wid * 1024);
  };
  auto stageB = [&](int tt) {
    const int b = tt & 3;
    const int k0 = tt * BK;
    load_lds16(B + (rowB0 + srow0) * K + k0 + scb0 * 16,
               lds + b * 32768 + 16384 + wid * 1024);
    load_lds16(B + (rowB0 + srow1) * K + k0 + scb1 * 16,
               lds + b * 32768 + 16384 + 8192 + wid * 1024);
  };

  // --- swizzled read column (byte) within a 64B LDS row ---
  const int rcol = ((kg ^ ((lrow >> 1) & 3)) << 4);

  // prologue: stage tiles 0 and 1 (8 loads outstanding per thread)
  stageA(0); stageB(0); stageA(1); stageB(1);

  for (int tt = 0; tt < nt; ++tt) {
    const int b = tt & 3;
    // wait for tile tt's loads (leave tile tt+1's 4 loads in flight)
    if (tt + 1 < nt) waitvm<4>(); else waitvm<0>();
    bar();  // the only barrier per tile

    const char* Abase = lds + b * 32768 + (wm * 128 + lrow) * 64 + rcol;
    const char* Bbase = lds + b * 32768 + 16384 + (wn * 64 + lrow) * 64 + rcol;

    i32x4 af[8], bf[4];
    #pragma unroll
    for (int m = 0; m < 8; ++m)
      af[m] = *(const i32x4*)(Abase + m * 1024);
    #pragma unroll
    for (int n = 0; n < 4; ++n)
      bf[n] = *(const i32x4*)(Bbase + n * 1024);

    if (tt + 2 < nt) { stageA(tt + 2); stageB(tt + 2); }

    #pragma unroll
    for (int m = 0; m < 8; ++m)
      #pragma unroll
      for (int n = 0; n < 4; ++n)
        acc[m][n] = __builtin_amdgcn_mfma_i32_16x16x64_i8(af[m], bf[n], acc[m][n], 0, 0, 0);
  }

  // --- epilogue: C/D layout col = lane&15, row = (lane>>4)*4 + r ---
  // i32 -> f32 conversion is exact (|sum| <= 4096)
  const size_t cRow0 = rowA0 + (size_t)wm * 128;
  const size_t cCol0 = rowB0 + (size_t)wn * 64;
  const int orow = kg * 4;
  #pragma unroll
  for (int m = 0; m < 8; ++m)
    #pragma unroll
    for (int n = 0; n < 4; ++n)
      #pragma unroll
      for (int r = 0; r < 4; ++r)
        C[(cRow0 + m * 16 + orow + r) * N + cCol0 + n * 16 + lrow] =
            (float)acc[m][n][r];
}

// ---------------------------------------------------------------------------
extern "C" void kernel_launch(void* const* d_in, const int* in_sizes, int n_in,
                              void* d_out, int out_size, void* d_ws, size_t ws_size,
                              hipStream_t stream) {
  const float* x = (const float*)d_in[0];
  const float* w = (const float*)d_in[1];
  float* out = (float*)d_out;

  const int K = 4096;
  const int M = in_sizes[0] / K;   // 8192
  const int N = in_sizes[1] / K;   // 4096

  signed char* xb = (signed char*)d_ws;
  signed char* wb = xb + (size_t)M * K;

  int n8x = (M * K) / 8;
  int n8w = (N * K) / 8;
  binarize_i8<<<dim3(2048), dim3(256), 0, stream>>>(x, xb, n8x);
  binarize_i8<<<dim3(2048), dim3(256), 0, stream>>>(w, wb, n8w);

  int nbm = M / 256;
  int nbn = N / 256;
  gemm_bt_i8<<<dim3(nbm * nbn), dim3(512), 0, stream>>>(
      xb, wb, out, M, N, K, nbn);
}